// Round 3
// baseline (555.325 us; speedup 1.0000x reference)
//
#include <hip/hip_runtime.h>

// OTPE single timestep on MI355X.
// Inputs: x[8192], W[8192,4096], u[4096], E[8192,4096], R_hat[8192,4096],
//         g_bar[4096], ratio[1]  (all f32)
// Outputs (concat): s[4096], u_new[4096], E_new[8192,4096], R_new[8192,4096],
//                   g_bar_new[4096], ratio_new[1]
//
// Kernel-side roofline: ~640 MB mandatory traffic -> ~100 us at 6.4 TB/s
// (fills measured at 6.5 TB/s). Round 3: (1) matvec occupancy 1->4 blocks/CU
// via NCHUNK=256, (2) elemwise loads back to cached (NT kept on stores only),
// testing the NT-load theory for elemwise's ~3.2 TB/s.

#define SIG_TAU 0.8807970779778823f  // sigmoid(2.0) in f32

typedef float f32x4 __attribute__((ext_vector_type(4)));

constexpr int N_IN  = 8192;
constexpr int N_OUT = 4096;
constexpr int NCG   = N_OUT / 4;          // 1024 float4 column-groups
constexpr int NCHUNK = 256;               // split-K chunks (4 MB partials)
constexpr int ROWS_PER_CHUNK = N_IN / NCHUNK;   // 32
constexpr int ROWS_PER_CHUNK_ATOM = 64;         // fallback path

// Output offsets (floats)
constexpr size_t OFF_S     = 0;
constexpr size_t OFF_U     = (size_t)N_OUT;                       // 4096
constexpr size_t OFF_E     = (size_t)2 * N_OUT;                   // 8192
constexpr size_t OFF_R     = OFF_E + (size_t)N_IN * N_OUT;        // 33562624
constexpr size_t OFF_G     = OFF_R + (size_t)N_IN * N_OUT;        // 67117056
constexpr size_t OFF_RATIO = OFF_G + (size_t)N_OUT;               // 67121152

// Split-K matvec, deterministic: each (cg, chunk) partial written exactly once.
// 1024 blocks = 4 blocks/CU = 16 waves/CU for HBM latency hiding.
__global__ __launch_bounds__(256) void matvec_split(
    const float* __restrict__ x, const f32x4* __restrict__ W4,
    f32x4* __restrict__ part4) {
    const int cg    = blockIdx.x * 256 + threadIdx.x;   // 0..1023
    const int chunk = blockIdx.y;                        // 0..255
    const int row0  = chunk * ROWS_PER_CHUNK;
    f32x4 a = {0.f, 0.f, 0.f, 0.f};
#pragma unroll 8
    for (int r = 0; r < ROWS_PER_CHUNK; ++r) {
        const float xv = x[row0 + r];
        const f32x4 w  = __builtin_nontemporal_load(
            &W4[(size_t)(row0 + r) * NCG + cg]);
        a[0] = fmaf(xv, w[0], a[0]);
        a[1] = fmaf(xv, w[1], a[1]);
        a[2] = fmaf(xv, w[2], a[2]);
        a[3] = fmaf(xv, w[3], a[3]);
    }
    part4[(size_t)chunk * NCG + cg] = a;   // plain store, no atomics
}

// Fallback if ws is too small for partials: atomicAdd path.
__global__ __launch_bounds__(256) void matvec_atomic(
    const float* __restrict__ x, const f32x4* __restrict__ W4,
    float* __restrict__ acc) {
    const int cg   = blockIdx.x * 256 + threadIdx.x;
    const int row0 = blockIdx.y * ROWS_PER_CHUNK_ATOM;
    f32x4 a = {0.f, 0.f, 0.f, 0.f};
#pragma unroll 8
    for (int r = 0; r < ROWS_PER_CHUNK_ATOM; ++r) {
        const float xv = x[row0 + r];
        const f32x4 w  = W4[(size_t)(row0 + r) * NCG + cg];
        a[0] = fmaf(xv, w[0], a[0]);
        a[1] = fmaf(xv, w[1], a[1]);
        a[2] = fmaf(xv, w[2], a[2]);
        a[3] = fmaf(xv, w[3], a[3]);
    }
    float* dst = acc + (size_t)cg * 4;
    atomicAdd(dst + 0, a[0]);
    atomicAdd(dst + 1, a[1]);
    atomicAdd(dst + 2, a[2]);
    atomicAdd(dst + 3, a[3]);
}

// Per-column: reduce split-K partials (L2-resident), spike, surrogate grad,
// soft reset, g_bar/ratio update.
__global__ __launch_bounds__(256) void finalize(
    const float* __restrict__ part, const int nchunks,
    const float* __restrict__ u, const float* __restrict__ g_bar,
    const float* __restrict__ ratio, float* __restrict__ out,
    float* __restrict__ sg_ws) {
    const int j = blockIdx.x * 256 + threadIdx.x;
    if (j >= N_OUT) return;
    float acc = 0.f;
#pragma unroll 8
    for (int c = 0; c < nchunks; ++c)
        acc += part[(size_t)c * N_OUT + j];   // coalesced across j

    const float u_pre = fmaf(SIG_TAU, u[j], acc);
    const float s     = (u_pre >= 1.0f) ? 1.0f : 0.0f;
    const float t     = 1.0f / fmaf(10.0f, fabsf(u_pre - 1.0f), 1.0f);
    const float sg    = t * t;                 // surrogate ds/du_pre
    const float u_new = u_pre - s;             // soft reset, V_TH=1

    const float r0        = SIG_TAU * ratio[0];
    const float ratio_new = r0 + 1.0f;
    const float r         = r0 / ratio_new;
    // ds_du_prev / sig_tau == sg
    const float g_new = fmaf(r, g_bar[j], (1.0f - r) * sg);

    out[OFF_S + j] = s;
    out[OFF_U + j] = u_new;
    out[OFF_G + j] = g_new;
    sg_ws[j] = sg;
    if (j == 0) out[OFF_RATIO] = ratio_new;
}

// Big streaming pass: E_new = sig_tau*E + x[i];
// R_new = sig_tau*R_hat + sg[j]*E_new.
// Loads CACHED (round-3 change: NT loads suspected of costing read BW);
// stores nontemporal (streamed once, never re-read by us).
__global__ __launch_bounds__(256) void elemwise(
    const float* __restrict__ x, const f32x4* __restrict__ E4,
    const f32x4* __restrict__ R4, const f32x4* __restrict__ sg4,
    f32x4* __restrict__ Enew4, f32x4* __restrict__ Rnew4) {
    const size_t total  = (size_t)N_IN * NCG;  // 8,388,608 float4 groups
    const size_t stride = (size_t)gridDim.x * blockDim.x;
    for (size_t idx = (size_t)blockIdx.x * blockDim.x + threadIdx.x;
         idx < total; idx += stride) {
        const int i  = (int)(idx >> 10);        // row (x index), NCG=1024
        const int cg = (int)(idx & (NCG - 1));  // column group
        const float xv = x[i];                  // broadcast within wave
        const f32x4 s4 = sg4[cg];               // 16 KB table, cache-resident
        const f32x4 e  = E4[idx];
        const f32x4 rr = R4[idx];
        f32x4 en, rn;
        en[0] = fmaf(SIG_TAU, e[0], xv);
        en[1] = fmaf(SIG_TAU, e[1], xv);
        en[2] = fmaf(SIG_TAU, e[2], xv);
        en[3] = fmaf(SIG_TAU, e[3], xv);
        rn[0] = fmaf(s4[0], en[0], SIG_TAU * rr[0]);
        rn[1] = fmaf(s4[1], en[1], SIG_TAU * rr[1]);
        rn[2] = fmaf(s4[2], en[2], SIG_TAU * rr[2]);
        rn[3] = fmaf(s4[3], en[3], SIG_TAU * rr[3]);
        __builtin_nontemporal_store(en, &Enew4[idx]);
        __builtin_nontemporal_store(rn, &Rnew4[idx]);
    }
}

extern "C" void kernel_launch(void* const* d_in, const int* in_sizes, int n_in,
                              void* d_out, int out_size, void* d_ws, size_t ws_size,
                              hipStream_t stream) {
    const float* x     = (const float*)d_in[0];
    const float* W     = (const float*)d_in[1];
    const float* u     = (const float*)d_in[2];
    const float* E     = (const float*)d_in[3];
    const float* R_hat = (const float*)d_in[4];
    const float* g_bar = (const float*)d_in[5];
    const float* ratio = (const float*)d_in[6];
    float* out = (float*)d_out;

    float* sg   = (float*)d_ws;            // [4096] surrogate grad
    float* part = sg + N_OUT;              // [NCHUNK*4096] split-K partials

    const size_t need = (size_t)(N_OUT + (size_t)NCHUNK * N_OUT) * sizeof(float);
    if (ws_size >= need) {
        // Deterministic split-K: no memset, no atomics.
        dim3 g1(NCG / 256, NCHUNK);        // (4, 256) = 1024 blocks
        matvec_split<<<g1, 256, 0, stream>>>(x, (const f32x4*)W, (f32x4*)part);
        finalize<<<N_OUT / 256, 256, 0, stream>>>(
            part, NCHUNK, u, g_bar, ratio, out, sg);
    } else {
        // Fallback: atomic accumulation (ws poisoned 0xAA -> must zero).
        hipMemsetAsync(part, 0, N_OUT * sizeof(float), stream);
        dim3 g1(NCG / 256, N_IN / ROWS_PER_CHUNK_ATOM);  // (4, 128)
        matvec_atomic<<<g1, 256, 0, stream>>>(x, (const f32x4*)W, part);
        finalize<<<N_OUT / 256, 256, 0, stream>>>(
            part, 1, u, g_bar, ratio, out, sg);
    }

    // Grid-stride streaming pass: 2048 blocks = 256 CU x 8 wg/CU.
    elemwise<<<2048, 256, 0, stream>>>(
        x, (const f32x4*)E, (const f32x4*)R_hat, (const f32x4*)sg,
        (f32x4*)(out + OFF_E), (f32x4*)(out + OFF_R));
}

// Round 4
// 538.685 us; speedup vs baseline: 1.0309x; 1.0309x over previous
//
#include <hip/hip_runtime.h>

// OTPE single timestep on MI355X.
// Inputs: x[8192], W[8192,4096], u[4096], E[8192,4096], R_hat[8192,4096],
//         g_bar[4096], ratio[1]  (all f32)
// Outputs (concat): s[4096], u_new[4096], E_new[8192,4096], R_new[8192,4096],
//                   g_bar_new[4096], ratio_new[1]
//
// Round 4: elemwise rewrite. R3 counters: elemwise 170us, 403MB actual HBM
// -> 2.37 TB/s, VALUBusy 2%, VGPR=12 (!). Diagnosis: ILP starvation (one
// iteration's 2 loads in flight, serialized) + NT stores at ~1.58 TB/s
// (~1/4 of the 6.5 TB/s plain-store fill rate). Fix: row-per-block-iter
// layout with 8 independent loads/thread in flight (VGPR ~60), sg hoisted
// out of loop, plain stores.

#define SIG_TAU 0.8807970779778823f  // sigmoid(2.0) in f32

typedef float f32x4 __attribute__((ext_vector_type(4)));

constexpr int N_IN  = 8192;
constexpr int N_OUT = 4096;
constexpr int NCG   = N_OUT / 4;          // 1024 float4 column-groups per row
constexpr int NCHUNK = 256;               // split-K chunks (4 MB partials)
constexpr int ROWS_PER_CHUNK = N_IN / NCHUNK;   // 32
constexpr int ROWS_PER_CHUNK_ATOM = 64;         // fallback path

// Output offsets (floats)
constexpr size_t OFF_S     = 0;
constexpr size_t OFF_U     = (size_t)N_OUT;                       // 4096
constexpr size_t OFF_E     = (size_t)2 * N_OUT;                   // 8192
constexpr size_t OFF_R     = OFF_E + (size_t)N_IN * N_OUT;        // 33562624
constexpr size_t OFF_G     = OFF_R + (size_t)N_IN * N_OUT;        // 67117056
constexpr size_t OFF_RATIO = OFF_G + (size_t)N_OUT;               // 67121152

// Split-K matvec, deterministic: each (cg, chunk) partial written exactly once.
// 1024 blocks = 4 blocks/CU = 16 waves/CU for HBM latency hiding.
__global__ __launch_bounds__(256) void matvec_split(
    const float* __restrict__ x, const f32x4* __restrict__ W4,
    f32x4* __restrict__ part4) {
    const int cg    = blockIdx.x * 256 + threadIdx.x;   // 0..1023
    const int chunk = blockIdx.y;                        // 0..255
    const int row0  = chunk * ROWS_PER_CHUNK;
    f32x4 a = {0.f, 0.f, 0.f, 0.f};
#pragma unroll 8
    for (int r = 0; r < ROWS_PER_CHUNK; ++r) {
        const float xv = x[row0 + r];
        const f32x4 w  = __builtin_nontemporal_load(
            &W4[(size_t)(row0 + r) * NCG + cg]);
        a[0] = fmaf(xv, w[0], a[0]);
        a[1] = fmaf(xv, w[1], a[1]);
        a[2] = fmaf(xv, w[2], a[2]);
        a[3] = fmaf(xv, w[3], a[3]);
    }
    part4[(size_t)chunk * NCG + cg] = a;   // plain store, no atomics
}

// Fallback if ws is too small for partials: atomicAdd path.
__global__ __launch_bounds__(256) void matvec_atomic(
    const float* __restrict__ x, const f32x4* __restrict__ W4,
    float* __restrict__ acc) {
    const int cg   = blockIdx.x * 256 + threadIdx.x;
    const int row0 = blockIdx.y * ROWS_PER_CHUNK_ATOM;
    f32x4 a = {0.f, 0.f, 0.f, 0.f};
#pragma unroll 8
    for (int r = 0; r < ROWS_PER_CHUNK_ATOM; ++r) {
        const float xv = x[row0 + r];
        const f32x4 w  = W4[(size_t)(row0 + r) * NCG + cg];
        a[0] = fmaf(xv, w[0], a[0]);
        a[1] = fmaf(xv, w[1], a[1]);
        a[2] = fmaf(xv, w[2], a[2]);
        a[3] = fmaf(xv, w[3], a[3]);
    }
    float* dst = acc + (size_t)cg * 4;
    atomicAdd(dst + 0, a[0]);
    atomicAdd(dst + 1, a[1]);
    atomicAdd(dst + 2, a[2]);
    atomicAdd(dst + 3, a[3]);
}

// Per-column: reduce split-K partials (L2-resident), spike, surrogate grad,
// soft reset, g_bar/ratio update.
__global__ __launch_bounds__(256) void finalize(
    const float* __restrict__ part, const int nchunks,
    const float* __restrict__ u, const float* __restrict__ g_bar,
    const float* __restrict__ ratio, float* __restrict__ out,
    float* __restrict__ sg_ws) {
    const int j = blockIdx.x * 256 + threadIdx.x;
    if (j >= N_OUT) return;
    float acc = 0.f;
#pragma unroll 8
    for (int c = 0; c < nchunks; ++c)
        acc += part[(size_t)c * N_OUT + j];   // coalesced across j

    const float u_pre = fmaf(SIG_TAU, u[j], acc);
    const float s     = (u_pre >= 1.0f) ? 1.0f : 0.0f;
    const float t     = 1.0f / fmaf(10.0f, fabsf(u_pre - 1.0f), 1.0f);
    const float sg    = t * t;                 // surrogate ds/du_pre
    const float u_new = u_pre - s;             // soft reset, V_TH=1

    const float r0        = SIG_TAU * ratio[0];
    const float ratio_new = r0 + 1.0f;
    const float r         = r0 / ratio_new;
    // ds_du_prev / sig_tau == sg
    const float g_new = fmaf(r, g_bar[j], (1.0f - r) * sg);

    out[OFF_S + j] = s;
    out[OFF_U + j] = u_new;
    out[OFF_G + j] = g_new;
    sg_ws[j] = sg;
    if (j == 0) out[OFF_RATIO] = ratio_new;
}

// Big streaming pass, row-per-block-iteration:
//   E_new = sig_tau*E + x[row];  R_new = sig_tau*R_hat + sg[j]*E_new.
// Each thread owns columns {tid, tid+256, tid+512, tid+768} of the row:
// 8 independent 16B loads in flight per thread, sg hoisted out of the loop,
// x[row] block-uniform. Plain (cached) loads and stores.
__global__ __launch_bounds__(256) void elemwise(
    const float* __restrict__ x, const f32x4* __restrict__ E4,
    const f32x4* __restrict__ R4, const f32x4* __restrict__ sg4,
    f32x4* __restrict__ Enew4, f32x4* __restrict__ Rnew4) {
    const int tid = threadIdx.x;
    // sg table: 4 vectors per thread, invariant across rows.
    const f32x4 s0 = sg4[tid];
    const f32x4 s1 = sg4[tid + 256];
    const f32x4 s2 = sg4[tid + 512];
    const f32x4 s3 = sg4[tid + 768];

    for (int row = blockIdx.x; row < N_IN; row += gridDim.x) {
        const float  xv   = x[row];                  // block-uniform scalar
        const size_t base = (size_t)row * NCG + tid;

        const f32x4 e0 = E4[base];
        const f32x4 e1 = E4[base + 256];
        const f32x4 e2 = E4[base + 512];
        const f32x4 e3 = E4[base + 768];
        const f32x4 r0 = R4[base];
        const f32x4 r1 = R4[base + 256];
        const f32x4 r2 = R4[base + 512];
        const f32x4 r3 = R4[base + 768];

        f32x4 en0, en1, en2, en3, rn0, rn1, rn2, rn3;
#define COMP(k)                                                   \
        en##k[0] = fmaf(SIG_TAU, e##k[0], xv);                    \
        en##k[1] = fmaf(SIG_TAU, e##k[1], xv);                    \
        en##k[2] = fmaf(SIG_TAU, e##k[2], xv);                    \
        en##k[3] = fmaf(SIG_TAU, e##k[3], xv);                    \
        rn##k[0] = fmaf(s##k[0], en##k[0], SIG_TAU * r##k[0]);    \
        rn##k[1] = fmaf(s##k[1], en##k[1], SIG_TAU * r##k[1]);    \
        rn##k[2] = fmaf(s##k[2], en##k[2], SIG_TAU * r##k[2]);    \
        rn##k[3] = fmaf(s##k[3], en##k[3], SIG_TAU * r##k[3]);
        COMP(0) COMP(1) COMP(2) COMP(3)
#undef COMP

        Enew4[base]       = en0;
        Enew4[base + 256] = en1;
        Enew4[base + 512] = en2;
        Enew4[base + 768] = en3;
        Rnew4[base]       = rn0;
        Rnew4[base + 256] = rn1;
        Rnew4[base + 512] = rn2;
        Rnew4[base + 768] = rn3;
    }
}

extern "C" void kernel_launch(void* const* d_in, const int* in_sizes, int n_in,
                              void* d_out, int out_size, void* d_ws, size_t ws_size,
                              hipStream_t stream) {
    const float* x     = (const float*)d_in[0];
    const float* W     = (const float*)d_in[1];
    const float* u     = (const float*)d_in[2];
    const float* E     = (const float*)d_in[3];
    const float* R_hat = (const float*)d_in[4];
    const float* g_bar = (const float*)d_in[5];
    const float* ratio = (const float*)d_in[6];
    float* out = (float*)d_out;

    float* sg   = (float*)d_ws;            // [4096] surrogate grad
    float* part = sg + N_OUT;              // [NCHUNK*4096] split-K partials

    const size_t need = (size_t)(N_OUT + (size_t)NCHUNK * N_OUT) * sizeof(float);
    if (ws_size >= need) {
        // Deterministic split-K: no memset, no atomics.
        dim3 g1(NCG / 256, NCHUNK);        // (4, 256) = 1024 blocks
        matvec_split<<<g1, 256, 0, stream>>>(x, (const f32x4*)W, (f32x4*)part);
        finalize<<<N_OUT / 256, 256, 0, stream>>>(
            part, NCHUNK, u, g_bar, ratio, out, sg);
    } else {
        // Fallback: atomic accumulation (ws poisoned 0xAA -> must zero).
        hipMemsetAsync(part, 0, N_OUT * sizeof(float), stream);
        dim3 g1(NCG / 256, N_IN / ROWS_PER_CHUNK_ATOM);  // (4, 128)
        matvec_atomic<<<g1, 256, 0, stream>>>(x, (const f32x4*)W, part);
        finalize<<<N_OUT / 256, 256, 0, stream>>>(
            part, 1, u, g_bar, ratio, out, sg);
    }

    // 2048 blocks = 8 wg/CU; 4 rows per block.
    elemwise<<<2048, 256, 0, stream>>>(
        x, (const f32x4*)E, (const f32x4*)R_hat, (const f32x4*)sg,
        (f32x4*)(out + OFF_E), (f32x4*)(out + OFF_R));
}

// Round 5
// 530.200 us; speedup vs baseline: 1.0474x; 1.0160x over previous
//
#include <hip/hip_runtime.h>

// OTPE single timestep on MI355X.
// Round 5: phase-split the big elemwise. R3/R4 evidence: elemwise stuck at
// ~150-170us (~2.5-3 TB/s) regardless of NT flags / ILP depth / layout,
// while poison fills hit 6.5 TB/s on the same buffers. Remaining suspect:
// 4 concurrent 128MB streams with per-iteration R/W turnaround. Split into
// two copy-like passes (1R+1W and 2R+1W), ordered so E_new is L3-hot for
// the R-pass re-read:  matvec -> ew_E -> finalize -> ew_R.

#define SIG_TAU 0.8807970779778823f  // sigmoid(2.0) in f32

typedef float f32x4 __attribute__((ext_vector_type(4)));

constexpr int N_IN  = 8192;
constexpr int N_OUT = 4096;
constexpr int NCG   = N_OUT / 4;          // 1024 float4 column-groups per row
constexpr int NCHUNK = 256;               // split-K chunks (4 MB partials)
constexpr int ROWS_PER_CHUNK = N_IN / NCHUNK;   // 32
constexpr int ROWS_PER_CHUNK_ATOM = 64;         // fallback path

// Output offsets (floats)
constexpr size_t OFF_S     = 0;
constexpr size_t OFF_U     = (size_t)N_OUT;                       // 4096
constexpr size_t OFF_E     = (size_t)2 * N_OUT;                   // 8192
constexpr size_t OFF_R     = OFF_E + (size_t)N_IN * N_OUT;        // 33562624
constexpr size_t OFF_G     = OFF_R + (size_t)N_IN * N_OUT;        // 67117056
constexpr size_t OFF_RATIO = OFF_G + (size_t)N_OUT;               // 67121152

// Split-K matvec, deterministic: each (cg, chunk) partial written exactly once.
__global__ __launch_bounds__(256) void matvec_split(
    const float* __restrict__ x, const f32x4* __restrict__ W4,
    f32x4* __restrict__ part4) {
    const int cg    = blockIdx.x * 256 + threadIdx.x;   // 0..1023
    const int chunk = blockIdx.y;                        // 0..255
    const int row0  = chunk * ROWS_PER_CHUNK;
    f32x4 a = {0.f, 0.f, 0.f, 0.f};
#pragma unroll 8
    for (int r = 0; r < ROWS_PER_CHUNK; ++r) {
        const float xv = x[row0 + r];
        const f32x4 w  = __builtin_nontemporal_load(
            &W4[(size_t)(row0 + r) * NCG + cg]);
        a[0] = fmaf(xv, w[0], a[0]);
        a[1] = fmaf(xv, w[1], a[1]);
        a[2] = fmaf(xv, w[2], a[2]);
        a[3] = fmaf(xv, w[3], a[3]);
    }
    part4[(size_t)chunk * NCG + cg] = a;   // plain store, no atomics
}

// Fallback if ws is too small for partials: atomicAdd path.
__global__ __launch_bounds__(256) void matvec_atomic(
    const float* __restrict__ x, const f32x4* __restrict__ W4,
    float* __restrict__ acc) {
    const int cg   = blockIdx.x * 256 + threadIdx.x;
    const int row0 = blockIdx.y * ROWS_PER_CHUNK_ATOM;
    f32x4 a = {0.f, 0.f, 0.f, 0.f};
#pragma unroll 8
    for (int r = 0; r < ROWS_PER_CHUNK_ATOM; ++r) {
        const float xv = x[row0 + r];
        const f32x4 w  = W4[(size_t)(row0 + r) * NCG + cg];
        a[0] = fmaf(xv, w[0], a[0]);
        a[1] = fmaf(xv, w[1], a[1]);
        a[2] = fmaf(xv, w[2], a[2]);
        a[3] = fmaf(xv, w[3], a[3]);
    }
    float* dst = acc + (size_t)cg * 4;
    atomicAdd(dst + 0, a[0]);
    atomicAdd(dst + 1, a[1]);
    atomicAdd(dst + 2, a[2]);
    atomicAdd(dst + 3, a[3]);
}

// Per-column: reduce split-K partials (L2/L3-resident), spike, surrogate
// grad, soft reset, g_bar/ratio update.
__global__ __launch_bounds__(256) void finalize(
    const float* __restrict__ part, const int nchunks,
    const float* __restrict__ u, const float* __restrict__ g_bar,
    const float* __restrict__ ratio, float* __restrict__ out,
    float* __restrict__ sg_ws) {
    const int j = blockIdx.x * 256 + threadIdx.x;
    if (j >= N_OUT) return;
    float acc = 0.f;
#pragma unroll 8
    for (int c = 0; c < nchunks; ++c)
        acc += part[(size_t)c * N_OUT + j];   // coalesced across j

    const float u_pre = fmaf(SIG_TAU, u[j], acc);
    const float s     = (u_pre >= 1.0f) ? 1.0f : 0.0f;
    const float t     = 1.0f / fmaf(10.0f, fabsf(u_pre - 1.0f), 1.0f);
    const float sg    = t * t;                 // surrogate ds/du_pre
    const float u_new = u_pre - s;             // soft reset, V_TH=1

    const float r0        = SIG_TAU * ratio[0];
    const float ratio_new = r0 + 1.0f;
    const float r         = r0 / ratio_new;
    // ds_du_prev / sig_tau == sg
    const float g_new = fmaf(r, g_bar[j], (1.0f - r) * sg);

    out[OFF_S + j] = s;
    out[OFF_U + j] = u_new;
    out[OFF_G + j] = g_new;
    sg_ws[j] = sg;
    if (j == 0) out[OFF_RATIO] = ratio_new;
}

// Phase 1 of the big pass: E_new = sig_tau*E + x[row].
// Pure 1-read-stream + 1-write-stream, copy-like. NT load on E (never
// reused); PLAIN store on E_new (re-read by ew_R — keep it in L3).
__global__ __launch_bounds__(256) void ew_E(
    const float* __restrict__ x, const f32x4* __restrict__ E4,
    f32x4* __restrict__ Enew4) {
    const int tid = threadIdx.x;
    for (int row = blockIdx.x; row < N_IN; row += gridDim.x) {
        const float  xv   = x[row];                  // block-uniform scalar
        const size_t base = (size_t)row * NCG + tid;
        const f32x4 e0 = __builtin_nontemporal_load(&E4[base]);
        const f32x4 e1 = __builtin_nontemporal_load(&E4[base + 256]);
        const f32x4 e2 = __builtin_nontemporal_load(&E4[base + 512]);
        const f32x4 e3 = __builtin_nontemporal_load(&E4[base + 768]);
        f32x4 en0, en1, en2, en3;
#define CE(k)                                      \
        en##k[0] = fmaf(SIG_TAU, e##k[0], xv);     \
        en##k[1] = fmaf(SIG_TAU, e##k[1], xv);     \
        en##k[2] = fmaf(SIG_TAU, e##k[2], xv);     \
        en##k[3] = fmaf(SIG_TAU, e##k[3], xv);
        CE(0) CE(1) CE(2) CE(3)
#undef CE
        Enew4[base]       = en0;
        Enew4[base + 256] = en1;
        Enew4[base + 512] = en2;
        Enew4[base + 768] = en3;
    }
}

// Phase 2: R_new = sig_tau*R_hat + sg[j]*E_new.
// R_hat NT load (no reuse), E_new plain load (L3-hot from ew_E),
// R_new NT store (never re-read; keep L3 for E_new).
__global__ __launch_bounds__(256) void ew_R(
    const f32x4* __restrict__ R4, const f32x4* __restrict__ Enew4,
    const f32x4* __restrict__ sg4, f32x4* __restrict__ Rnew4) {
    const int tid = threadIdx.x;
    const f32x4 s0 = sg4[tid];
    const f32x4 s1 = sg4[tid + 256];
    const f32x4 s2 = sg4[tid + 512];
    const f32x4 s3 = sg4[tid + 768];
    for (int row = blockIdx.x; row < N_IN; row += gridDim.x) {
        const size_t base = (size_t)row * NCG + tid;
        const f32x4 r0 = __builtin_nontemporal_load(&R4[base]);
        const f32x4 r1 = __builtin_nontemporal_load(&R4[base + 256]);
        const f32x4 r2 = __builtin_nontemporal_load(&R4[base + 512]);
        const f32x4 r3 = __builtin_nontemporal_load(&R4[base + 768]);
        const f32x4 en0 = Enew4[base];
        const f32x4 en1 = Enew4[base + 256];
        const f32x4 en2 = Enew4[base + 512];
        const f32x4 en3 = Enew4[base + 768];
        f32x4 rn0, rn1, rn2, rn3;
#define CR(k)                                                     \
        rn##k[0] = fmaf(s##k[0], en##k[0], SIG_TAU * r##k[0]);    \
        rn##k[1] = fmaf(s##k[1], en##k[1], SIG_TAU * r##k[1]);    \
        rn##k[2] = fmaf(s##k[2], en##k[2], SIG_TAU * r##k[2]);    \
        rn##k[3] = fmaf(s##k[3], en##k[3], SIG_TAU * r##k[3]);
        CR(0) CR(1) CR(2) CR(3)
#undef CR
        __builtin_nontemporal_store(rn0, &Rnew4[base]);
        __builtin_nontemporal_store(rn1, &Rnew4[base + 256]);
        __builtin_nontemporal_store(rn2, &Rnew4[base + 512]);
        __builtin_nontemporal_store(rn3, &Rnew4[base + 768]);
    }
}

extern "C" void kernel_launch(void* const* d_in, const int* in_sizes, int n_in,
                              void* d_out, int out_size, void* d_ws, size_t ws_size,
                              hipStream_t stream) {
    const float* x     = (const float*)d_in[0];
    const float* W     = (const float*)d_in[1];
    const float* u     = (const float*)d_in[2];
    const float* E     = (const float*)d_in[3];
    const float* R_hat = (const float*)d_in[4];
    const float* g_bar = (const float*)d_in[5];
    const float* ratio = (const float*)d_in[6];
    float* out = (float*)d_out;

    float* sg   = (float*)d_ws;            // [4096] surrogate grad
    float* part = sg + N_OUT;              // [NCHUNK*4096] split-K partials

    f32x4* Enew4 = (f32x4*)(out + OFF_E);
    f32x4* Rnew4 = (f32x4*)(out + OFF_R);

    const size_t need = (size_t)(N_OUT + (size_t)NCHUNK * N_OUT) * sizeof(float);
    if (ws_size >= need) {
        dim3 g1(NCG / 256, NCHUNK);        // (4, 256) = 1024 blocks
        matvec_split<<<g1, 256, 0, stream>>>(x, (const f32x4*)W, (f32x4*)part);
        // E-pass is independent of the matvec: run it between matvec and
        // finalize so E_new is the freshest data in L3 when ew_R starts.
        ew_E<<<2048, 256, 0, stream>>>(x, (const f32x4*)E, Enew4);
        finalize<<<N_OUT / 256, 256, 0, stream>>>(
            part, NCHUNK, u, g_bar, ratio, out, sg);
    } else {
        hipMemsetAsync(part, 0, N_OUT * sizeof(float), stream);
        dim3 g1(NCG / 256, N_IN / ROWS_PER_CHUNK_ATOM);  // (4, 128)
        matvec_atomic<<<g1, 256, 0, stream>>>(x, (const f32x4*)W, part);
        ew_E<<<2048, 256, 0, stream>>>(x, (const f32x4*)E, Enew4);
        finalize<<<N_OUT / 256, 256, 0, stream>>>(
            part, 1, u, g_bar, ratio, out, sg);
    }

    ew_R<<<2048, 256, 0, stream>>>(
        (const f32x4*)R_hat, (const f32x4*)Enew4, (const f32x4*)sg, Rnew4);
}